// Round 1
// baseline (3943.037 us; speedup 1.0000x reference)
//
#include <hip/hip_runtime.h>
#include <math.h>

#define T 2048
#define C 128
#define BATCH 8
#define NLAYER 10

__device__ __forceinline__ float sigmoidf_(float x) {
    return 1.f / (1.f + __expf(-x));
}
__device__ __forceinline__ float tanhf_(float x) {
    float a = fabsf(x);
    float e = __expf(-2.f * a);
    float t = (1.f - e) / (1.f + e);
    return copysignf(t, x);
}

// ---------------- init: h = x*Wc + bc ; skip = 0 ----------------
__global__ void k_init(const float* __restrict__ x, const float* __restrict__ Wc,
                       const float* __restrict__ bc, float* __restrict__ h,
                       float* __restrict__ skip) {
    int i = blockIdx.x * 256 + threadIdx.x;   // over B*T*C
    int c = i & 127;
    int pos = i >> 7;
    h[i] = x[pos] * Wc[c] + bc[c];
    skip[i] = 0.f;
}

// ---------------- one WaveNet block ----------------
// grid: T/4 blocks, block: 128 threads (k = channel)
// tile: all 8 batches x 4 time steps = 32 rows
__global__ __launch_bounds__(128) void k_layer(
    const float* __restrict__ h_in, float* __restrict__ h_out,
    float* __restrict__ skip, const float* __restrict__ cond,
    const float* __restrict__ Wt, const float* __restrict__ bt,
    const float* __restrict__ Ws, const float* __restrict__ bs,
    const float* __restrict__ Dt, const float* __restrict__ Bt,
    const float* __restrict__ Ds, const float* __restrict__ Bs,
    const float* __restrict__ Wskip, const float* __restrict__ bskip,
    const float* __restrict__ Wres, const float* __restrict__ bres,
    int l, int d)
{
    __shared__ float smem[3 * 128 * 34 + 128];
    float* hs = smem;                  // [seg][ci][34] rows of h (r = b*4+p)
    float* conds = smem + 3 * 128 * 34;
    const int k = threadIdx.x;
    const int t0 = blockIdx.x * 4;

    conds[k] = cond[k];                // cond is [8][16] = 128 floats

    // stage h segments (t-d, t, t+d)
    #pragma unroll
    for (int seg = 0; seg < 3; ++seg) {
        int dt = (seg - 1) * d;
        #pragma unroll
        for (int r = 0; r < 32; ++r) {
            int b = r >> 2, p = r & 3;
            int t = t0 + p + dt;
            float v = 0.f;
            if (t >= 0 && t < T) v = h_in[(b * T + t) * C + k];
            hs[(seg * 128 + k) * 34 + r] = v;
        }
    }
    __syncthreads();

    float acct[32], accs[32];
    {
        float btv = bt[l * C + k], bsv = bs[l * C + k];
        float Btv[4], Bsv[4];
        #pragma unroll
        for (int p = 0; p < 4; ++p) {
            Btv[p] = Bt[(l * T + t0 + p) * C + k];
            Bsv[p] = Bs[(l * T + t0 + p) * C + k];
        }
        #pragma unroll
        for (int r = 0; r < 32; ++r) {
            acct[r] = btv + Btv[r & 3];
            accs[r] = bsv + Bsv[r & 3];
        }
    }

    // conditioning: acc += cond[b,:] . D[l,:,t,k]  (each D element read ONCE)
    #pragma unroll
    for (int c = 0; c < 16; ++c) {
        float dtv[4], dsv[4];
        #pragma unroll
        for (int p = 0; p < 4; ++p) {
            dtv[p] = Dt[((l * 16 + c) * T + t0 + p) * C + k];
            dsv[p] = Ds[((l * 16 + c) * T + t0 + p) * C + k];
        }
        #pragma unroll
        for (int b = 0; b < 8; ++b) {
            float cv = conds[b * 16 + c];
            #pragma unroll
            for (int p = 0; p < 4; ++p) {
                acct[b * 4 + p] = fmaf(cv, dtv[p], acct[b * 4 + p]);
                accs[b * 4 + p] = fmaf(cv, dsv[p], accs[b * 4 + p]);
            }
        }
    }

    // dilated conv over input channels
    const float* WtL = Wt + l * 3 * C * C + k;
    const float* WsL = Ws + l * 3 * C * C + k;
    for (int ci = 0; ci < C; ++ci) {
        float wt0 = WtL[ci * C];
        float wt1 = WtL[C * C + ci * C];
        float wt2 = WtL[2 * C * C + ci * C];
        float ws0 = WsL[ci * C];
        float ws1 = WsL[C * C + ci * C];
        float ws2 = WsL[2 * C * C + ci * C];
        const float* h0r = &hs[(0 * 128 + ci) * 34];
        const float* h1r = &hs[(1 * 128 + ci) * 34];
        const float* h2r = &hs[(2 * 128 + ci) * 34];
        #pragma unroll
        for (int r = 0; r < 32; r += 2) {
            float2 a0 = *(const float2*)(h0r + r);
            float2 a1 = *(const float2*)(h1r + r);
            float2 a2 = *(const float2*)(h2r + r);
            acct[r]     = fmaf(a0.x, wt0, fmaf(a1.x, wt1, fmaf(a2.x, wt2, acct[r])));
            acct[r + 1] = fmaf(a0.y, wt0, fmaf(a1.y, wt1, fmaf(a2.y, wt2, acct[r + 1])));
            accs[r]     = fmaf(a0.x, ws0, fmaf(a1.x, ws1, fmaf(a2.x, ws2, accs[r])));
            accs[r + 1] = fmaf(a0.y, ws0, fmaf(a1.y, ws1, fmaf(a2.y, ws2, accs[r + 1])));
        }
    }

    // gate
    #pragma unroll
    for (int r = 0; r < 32; ++r)
        acct[r] = tanhf_(acct[r]) * sigmoidf_(accs[r]);

    __syncthreads();                    // everyone done reading hs
    #pragma unroll
    for (int r = 0; r < 32; ++r)
        smem[k * 34 + r] = acct[r];     // g reuses hs[0] region: gs[ci][r]
    __syncthreads();

    // 1x1 skip / res convs
    float acck[32], accr[32];
    {
        float bk = bskip[l * C + k], br = bres[l * C + k];
        #pragma unroll
        for (int r = 0; r < 32; ++r) { acck[r] = bk; accr[r] = br; }
    }
    const float* WkL = Wskip + l * C * C + k;
    const float* WrL = Wres + l * C * C + k;
    for (int ci = 0; ci < C; ++ci) {
        float wk = WkL[ci * C];
        float wr = WrL[ci * C];
        const float* gr = &smem[ci * 34];
        #pragma unroll
        for (int r = 0; r < 32; r += 2) {
            float2 g2 = *(const float2*)(gr + r);
            acck[r]     = fmaf(g2.x, wk, acck[r]);
            accr[r]     = fmaf(g2.x, wr, accr[r]);
            acck[r + 1] = fmaf(g2.y, wk, acck[r + 1]);
            accr[r + 1] = fmaf(g2.y, wr, accr[r + 1]);
        }
    }

    #pragma unroll
    for (int r = 0; r < 32; ++r) {
        int b = r >> 2, p = r & 3;
        int idx = (b * T + t0 + p) * C + k;
        skip[idx] += acck[r];
        h_out[idx] = accr[r] + h_in[idx];
    }
}

// ---------------- head conv1: 128 -> 2048, k=3, relu ----------------
// grid: (T/8, nb), block 256; thread covers o = tid*8 .. tid*8+7, 8 time rows
__global__ __launch_bounds__(256) void k_conv1(
    const float* __restrict__ skip, const float* __restrict__ W1,
    const float* __restrict__ b1, float* __restrict__ out1, int b0)
{
    __shared__ float sl[128 * 10];      // [c][pp], rows t0-1..t0+8
    const int tid = threadIdx.x;
    const int t0 = blockIdx.x * 8;
    const int bl = blockIdx.y;
    const int b  = b0 + bl;

    for (int idx = tid; idx < 1280; idx += 256) {
        int c = idx / 10, pp = idx % 10;
        int t = t0 - 1 + pp;
        float v = 0.f;
        if (t >= 0 && t < T) v = skip[(b * T + t) * C + c];
        sl[c * 10 + pp] = v;
    }
    __syncthreads();

    float acc[8][8];
    #pragma unroll
    for (int p = 0; p < 8; ++p)
        #pragma unroll
        for (int u = 0; u < 8; ++u) acc[p][u] = 0.f;

    const float* Wp = W1 + tid * 8;
    for (int c = 0; c < 128; ++c) {
        float s[10];
        const float* row = &sl[c * 10];
        #pragma unroll
        for (int i = 0; i < 10; i += 2) {
            float2 v = *(const float2*)(row + i);
            s[i] = v.x; s[i + 1] = v.y;
        }
        #pragma unroll
        for (int j = 0; j < 3; ++j) {
            const float* wrow = Wp + (size_t)(j * 128 + c) * 2048;
            float4 wa = *(const float4*)(wrow);
            float4 wb = *(const float4*)(wrow + 4);
            #pragma unroll
            for (int p = 0; p < 8; ++p) {
                float sv = s[p + j];
                acc[p][0] = fmaf(sv, wa.x, acc[p][0]);
                acc[p][1] = fmaf(sv, wa.y, acc[p][1]);
                acc[p][2] = fmaf(sv, wa.z, acc[p][2]);
                acc[p][3] = fmaf(sv, wa.w, acc[p][3]);
                acc[p][4] = fmaf(sv, wb.x, acc[p][4]);
                acc[p][5] = fmaf(sv, wb.y, acc[p][5]);
                acc[p][6] = fmaf(sv, wb.z, acc[p][6]);
                acc[p][7] = fmaf(sv, wb.w, acc[p][7]);
            }
        }
    }

    float4 ba = *(const float4*)(b1 + tid * 8);
    float4 bb = *(const float4*)(b1 + tid * 8 + 4);
    #pragma unroll
    for (int p = 0; p < 8; ++p) {
        int t = t0 + p;
        float* op = out1 + ((size_t)bl * T + t) * 2048 + tid * 8;
        float4 oa, ob;
        oa.x = fmaxf(acc[p][0] + ba.x, 0.f);
        oa.y = fmaxf(acc[p][1] + ba.y, 0.f);
        oa.z = fmaxf(acc[p][2] + ba.z, 0.f);
        oa.w = fmaxf(acc[p][3] + ba.w, 0.f);
        ob.x = fmaxf(acc[p][4] + bb.x, 0.f);
        ob.y = fmaxf(acc[p][5] + bb.y, 0.f);
        ob.z = fmaxf(acc[p][6] + bb.z, 0.f);
        ob.w = fmaxf(acc[p][7] + bb.w, 0.f);
        *(float4*)(op) = oa;
        *(float4*)(op + 4) = ob;
    }
}

// ---------------- head conv2: 2048 -> 256, k=3, relu ----------------
// grid: (T/16, nb), block 128; thread covers o = tid*2, 16 time rows
__global__ __launch_bounds__(128) void k_conv2(
    const float* __restrict__ out1, const float* __restrict__ W2,
    const float* __restrict__ b2, float* __restrict__ out2, int b0)
{
    const int tid = threadIdx.x;
    const int t0 = blockIdx.x * 16;
    const int bl = blockIdx.y;
    const int b  = b0 + bl;
    const int o = tid * 2;

    float acc0[16], acc1[16];
    #pragma unroll
    for (int p = 0; p < 16; ++p) { acc0[p] = 0.f; acc1[p] = 0.f; }

    const float* A = out1 + (size_t)bl * T * 2048;
    for (int c = 0; c < 2048; ++c) {
        float s[18];
        #pragma unroll
        for (int pp = 0; pp < 18; ++pp) {
            int t = t0 - 1 + pp;
            s[pp] = (t >= 0 && t < T) ? A[(size_t)t * 2048 + c] : 0.f;
        }
        #pragma unroll
        for (int j = 0; j < 3; ++j) {
            float2 w = *(const float2*)(W2 + (size_t)(j * 2048 + c) * 256 + o);
            #pragma unroll
            for (int p = 0; p < 16; ++p) {
                float sv = s[p + j];
                acc0[p] = fmaf(sv, w.x, acc0[p]);
                acc1[p] = fmaf(sv, w.y, acc1[p]);
            }
        }
    }

    float2 bb = *(const float2*)(b2 + o);
    #pragma unroll
    for (int p = 0; p < 16; ++p) {
        int t = t0 + p;
        float2 ov;
        ov.x = fmaxf(acc0[p] + bb.x, 0.f);
        ov.y = fmaxf(acc1[p] + bb.y, 0.f);
        *(float2*)(out2 + ((size_t)(b * T) + t) * 256 + o) = ov;
    }
}

// ---------------- head conv3: 256 -> 1, k=1, tanh ----------------
// block 256 = 4 waves, each wave reduces one (b,t)
__global__ __launch_bounds__(256) void k_conv3(
    const float* __restrict__ out2, const float* __restrict__ W3,
    const float* __restrict__ b3, float* __restrict__ out)
{
    int wid = threadIdx.x >> 6, lane = threadIdx.x & 63;
    int pos = blockIdx.x * 4 + wid;
    float4 v = *(const float4*)(out2 + (size_t)pos * 256 + lane * 4);
    float4 w = *(const float4*)(W3 + lane * 4);
    float sum = v.x * w.x + v.y * w.y + v.z * w.z + v.w * w.w;
    #pragma unroll
    for (int off = 32; off > 0; off >>= 1) sum += __shfl_down(sum, off);
    if (lane == 0) out[pos] = tanhf_(sum + b3[0]);
}

extern "C" void kernel_launch(void* const* d_in, const int* in_sizes, int n_in,
                              void* d_out, int out_size, void* d_ws, size_t ws_size,
                              hipStream_t stream)
{
    const float* x     = (const float*)d_in[0];
    const float* cond  = (const float*)d_in[1];
    const float* Wc    = (const float*)d_in[2];
    const float* bc    = (const float*)d_in[3];
    const float* Wt    = (const float*)d_in[4];
    const float* bt    = (const float*)d_in[5];
    const float* Ws    = (const float*)d_in[6];
    const float* bs    = (const float*)d_in[7];
    const float* Dt    = (const float*)d_in[8];
    const float* Bt    = (const float*)d_in[9];
    const float* Ds    = (const float*)d_in[10];
    const float* Bs    = (const float*)d_in[11];
    const float* Wskip = (const float*)d_in[12];
    const float* bskip = (const float*)d_in[13];
    const float* Wres  = (const float*)d_in[14];
    const float* bres  = (const float*)d_in[15];
    const float* W1    = (const float*)d_in[16];
    const float* b1    = (const float*)d_in[17];
    const float* W2    = (const float*)d_in[18];
    const float* b2    = (const float*)d_in[19];
    const float* W3    = (const float*)d_in[20];
    const float* b3    = (const float*)d_in[21];
    float* out = (float*)d_out;

    float* ws   = (float*)d_ws;
    float* h0   = ws;                     // 2,097,152 floats
    float* h1   = ws + 2097152;           // 2,097,152
    float* skip = ws + 4194304;           // 2,097,152
    float* out2 = ws + 6291456;           // 4,194,304 (full [B,T,256])
    float* out1b= ws + 10485760;          // nb * T * 2048

    // pick largest batch-chunk for the head that fits the workspace
    int nb = 8;
    while (nb > 1 && (10485760ull + (size_t)nb * T * 2048ull) * 4ull > ws_size)
        nb >>= 1;

    k_init<<<8192, 256, 0, stream>>>(x, Wc, bc, h0, skip);

    static const int DIL[NLAYER] = {1, 2, 4, 8, 16, 32, 64, 128, 256, 512};
    float* hin = h0;
    float* hout = h1;
    for (int l = 0; l < NLAYER; ++l) {
        k_layer<<<T / 4, 128, 0, stream>>>(hin, hout, skip, cond,
                                           Wt, bt, Ws, bs, Dt, Bt, Ds, Bs,
                                           Wskip, bskip, Wres, bres,
                                           l, DIL[l]);
        float* tmp = hin; hin = hout; hout = tmp;
    }

    for (int b0 = 0; b0 < BATCH; b0 += nb) {
        int nbc = (b0 + nb <= BATCH) ? nb : (BATCH - b0);
        dim3 g1(T / 8, nbc), g2(T / 16, nbc);
        k_conv1<<<g1, 256, 0, stream>>>(skip, W1, b1, out1b, b0);
        k_conv2<<<g2, 128, 0, stream>>>(out1b, W2, b2, out2, b0);
    }

    k_conv3<<<(BATCH * T) / 4, 256, 0, stream>>>(out2, W3, b3, out);
}

// Round 2
// 2012.576 us; speedup vs baseline: 1.9592x; 1.9592x over previous
//
#include <hip/hip_runtime.h>
#include <hip/hip_bf16.h>
#include <math.h>

#define T 2048
#define C 128
#define BATCH 8
#define NLAYER 10

typedef short bf16x8 __attribute__((ext_vector_type(8)));
typedef float f32x4 __attribute__((ext_vector_type(4)));

__device__ __forceinline__ float sigmoidf_(float x) {
    return 1.f / (1.f + __expf(-x));
}
__device__ __forceinline__ float tanhf_(float x) {
    float a = fabsf(x);
    float e = __expf(-2.f * a);
    float t = (1.f - e) / (1.f + e);
    return copysignf(t, x);
}
__device__ __forceinline__ ushort f2bf(float v) {
    __hip_bfloat16 h = __float2bfloat16(v);
    return *reinterpret_cast<ushort*>(&h);
}

// ---------------- init: h = x*Wc + bc ; skip = 0 ----------------
__global__ void k_init(const float* __restrict__ x, const float* __restrict__ Wc,
                       const float* __restrict__ bc, float* __restrict__ h,
                       float* __restrict__ skip) {
    int i = blockIdx.x * 256 + threadIdx.x;   // over B*T*C
    int c = i & 127;
    int pos = i >> 7;
    h[i] = x[pos] * Wc[c] + bc[c];
    skip[i] = 0.f;
}

// ---------------- one WaveNet block (unchanged from round 1) ----------------
__global__ __launch_bounds__(128) void k_layer(
    const float* __restrict__ h_in, float* __restrict__ h_out,
    float* __restrict__ skip, const float* __restrict__ cond,
    const float* __restrict__ Wt, const float* __restrict__ bt,
    const float* __restrict__ Ws, const float* __restrict__ bs,
    const float* __restrict__ Dt, const float* __restrict__ Bt,
    const float* __restrict__ Ds, const float* __restrict__ Bs,
    const float* __restrict__ Wskip, const float* __restrict__ bskip,
    const float* __restrict__ Wres, const float* __restrict__ bres,
    int l, int d)
{
    __shared__ float smem[3 * 128 * 34 + 128];
    float* hs = smem;                  // [seg][ci][34] rows of h (r = b*4+p)
    float* conds = smem + 3 * 128 * 34;
    const int k = threadIdx.x;
    const int t0 = blockIdx.x * 4;

    conds[k] = cond[k];                // cond is [8][16] = 128 floats

    #pragma unroll
    for (int seg = 0; seg < 3; ++seg) {
        int dt = (seg - 1) * d;
        #pragma unroll
        for (int r = 0; r < 32; ++r) {
            int b = r >> 2, p = r & 3;
            int t = t0 + p + dt;
            float v = 0.f;
            if (t >= 0 && t < T) v = h_in[(b * T + t) * C + k];
            hs[(seg * 128 + k) * 34 + r] = v;
        }
    }
    __syncthreads();

    float acct[32], accs[32];
    {
        float btv = bt[l * C + k], bsv = bs[l * C + k];
        float Btv[4], Bsv[4];
        #pragma unroll
        for (int p = 0; p < 4; ++p) {
            Btv[p] = Bt[(l * T + t0 + p) * C + k];
            Bsv[p] = Bs[(l * T + t0 + p) * C + k];
        }
        #pragma unroll
        for (int r = 0; r < 32; ++r) {
            acct[r] = btv + Btv[r & 3];
            accs[r] = bsv + Bsv[r & 3];
        }
    }

    #pragma unroll
    for (int c = 0; c < 16; ++c) {
        float dtv[4], dsv[4];
        #pragma unroll
        for (int p = 0; p < 4; ++p) {
            dtv[p] = Dt[((l * 16 + c) * T + t0 + p) * C + k];
            dsv[p] = Ds[((l * 16 + c) * T + t0 + p) * C + k];
        }
        #pragma unroll
        for (int b = 0; b < 8; ++b) {
            float cv = conds[b * 16 + c];
            #pragma unroll
            for (int p = 0; p < 4; ++p) {
                acct[b * 4 + p] = fmaf(cv, dtv[p], acct[b * 4 + p]);
                accs[b * 4 + p] = fmaf(cv, dsv[p], accs[b * 4 + p]);
            }
        }
    }

    const float* WtL = Wt + l * 3 * C * C + k;
    const float* WsL = Ws + l * 3 * C * C + k;
    for (int ci = 0; ci < C; ++ci) {
        float wt0 = WtL[ci * C];
        float wt1 = WtL[C * C + ci * C];
        float wt2 = WtL[2 * C * C + ci * C];
        float ws0 = WsL[ci * C];
        float ws1 = WsL[C * C + ci * C];
        float ws2 = WsL[2 * C * C + ci * C];
        const float* h0r = &hs[(0 * 128 + ci) * 34];
        const float* h1r = &hs[(1 * 128 + ci) * 34];
        const float* h2r = &hs[(2 * 128 + ci) * 34];
        #pragma unroll
        for (int r = 0; r < 32; r += 2) {
            float2 a0 = *(const float2*)(h0r + r);
            float2 a1 = *(const float2*)(h1r + r);
            float2 a2 = *(const float2*)(h2r + r);
            acct[r]     = fmaf(a0.x, wt0, fmaf(a1.x, wt1, fmaf(a2.x, wt2, acct[r])));
            acct[r + 1] = fmaf(a0.y, wt0, fmaf(a1.y, wt1, fmaf(a2.y, wt2, acct[r + 1])));
            accs[r]     = fmaf(a0.x, ws0, fmaf(a1.x, ws1, fmaf(a2.x, ws2, accs[r])));
            accs[r + 1] = fmaf(a0.y, ws0, fmaf(a1.y, ws1, fmaf(a2.y, ws2, accs[r + 1])));
        }
    }

    #pragma unroll
    for (int r = 0; r < 32; ++r)
        acct[r] = tanhf_(acct[r]) * sigmoidf_(accs[r]);

    __syncthreads();
    #pragma unroll
    for (int r = 0; r < 32; ++r)
        smem[k * 34 + r] = acct[r];
    __syncthreads();

    float acck[32], accr[32];
    {
        float bk = bskip[l * C + k], br = bres[l * C + k];
        #pragma unroll
        for (int r = 0; r < 32; ++r) { acck[r] = bk; accr[r] = br; }
    }
    const float* WkL = Wskip + l * C * C + k;
    const float* WrL = Wres + l * C * C + k;
    for (int ci = 0; ci < C; ++ci) {
        float wk = WkL[ci * C];
        float wr = WrL[ci * C];
        const float* gr = &smem[ci * 34];
        #pragma unroll
        for (int r = 0; r < 32; r += 2) {
            float2 g2 = *(const float2*)(gr + r);
            acck[r]     = fmaf(g2.x, wk, acck[r]);
            accr[r]     = fmaf(g2.x, wr, accr[r]);
            acck[r + 1] = fmaf(g2.y, wk, acck[r + 1]);
            accr[r + 1] = fmaf(g2.y, wr, accr[r + 1]);
        }
    }

    #pragma unroll
    for (int r = 0; r < 32; ++r) {
        int b = r >> 2, p = r & 3;
        int idx = (b * T + t0 + p) * C + k;
        skip[idx] += acck[r];
        h_out[idx] = accr[r] + h_in[idx];
    }
}

// ---------------- bf16 converts / weight transposes ----------------
__global__ void k_f32_to_bf16(const float* __restrict__ in, ushort* __restrict__ out, int n) {
    int i = blockIdx.x * 256 + threadIdx.x;
    if (i < n) out[i] = f2bf(in[i]);
}

// W [3][KIN][N] f32 -> Wb [N][3*KIN] bf16; grid.x = N
template<int KIN>
__global__ void k_prep_w(const float* __restrict__ W, ushort* __restrict__ Wb, int N) {
    int n = blockIdx.x;
    for (int k = threadIdx.x; k < 3 * KIN; k += blockDim.x)
        Wb[(size_t)n * (3 * KIN) + k] = f2bf(W[(size_t)k * N + n]);
}

// ---------------- MFMA conv head: out[b,t,n] = relu(sum_{j,c} A[b,t-1+j,c]*W[j,c,n] + bias[n])
// A bf16 [B][T][KIN], Wb bf16 [N][3*KIN], grid (T/64, N/128, B), block 256 (4 waves)
// wave w: m_off=(w&1)*32, n_off=(w>>1)*64; per wave 2x4 tiles of 16x16, K-chunk 32.
template<int KIN, bool OUT_BF16>
__global__ __launch_bounds__(256) void k_conv_mfma(
    const ushort* __restrict__ A, const ushort* __restrict__ Wb,
    const float* __restrict__ bias, void* __restrict__ outv)
{
    constexpr int AS = 40;                 // LDS row stride in bf16 (80 B, 16B-aligned, 2-way banks = free)
    __shared__ ushort As[66 * AS];         // rows t0-1 .. t0+64, 32 c
    __shared__ ushort Bs[3 * 128 * AS];    // [j][n][32 k]

    const int tid  = threadIdx.x;
    const int lane = tid & 63;
    const int ln16 = lane & 15;
    const int quad = lane >> 4;
    const int wave = tid >> 6;
    const int m_off = (wave & 1) * 32;
    const int n_off = (wave >> 1) * 64;

    const int t0 = blockIdx.x * 64;
    const int n0 = blockIdx.y * 128;
    const int b  = blockIdx.z;
    const int N  = gridDim.y * 128;

    const ushort* Ab = A + (size_t)b * T * KIN;

    f32x4 acc[2][4];
    #pragma unroll
    for (int mi = 0; mi < 2; ++mi)
        #pragma unroll
        for (int ni = 0; ni < 4; ++ni)
            acc[mi][ni] = (f32x4){0.f, 0.f, 0.f, 0.f};

    for (int cc = 0; cc < KIN / 32; ++cc) {
        // stage A: 66 rows x 32 c, 16B per task
        for (int idx = tid; idx < 66 * 4; idx += 256) {
            int r = idx >> 2, part = idx & 3;
            int t = t0 - 1 + r;
            uint4 v = make_uint4(0u, 0u, 0u, 0u);
            if (t >= 0 && t < T)
                v = *(const uint4*)(Ab + (size_t)t * KIN + cc * 32 + part * 8);
            *(uint4*)(&As[r * AS + part * 8]) = v;
        }
        // stage B: 3 taps x 128 n x 32 k
        #pragma unroll
        for (int it = 0; it < 6; ++it) {
            int idx = tid + it * 256;
            int jr = idx >> 2, part = idx & 3;      // jr = j*128 + n
            int j = jr >> 7, n = jr & 127;
            uint4 v = *(const uint4*)(Wb + (size_t)(n0 + n) * (3 * KIN) + j * KIN + cc * 32 + part * 8);
            *(uint4*)(&Bs[jr * AS + part * 8]) = v;
        }
        __syncthreads();

        #pragma unroll
        for (int j = 0; j < 3; ++j) {
            bf16x8 af[2], bf[4];
            #pragma unroll
            for (int mi = 0; mi < 2; ++mi)
                af[mi] = *(const bf16x8*)(&As[(m_off + mi * 16 + ln16 + j) * AS + quad * 8]);
            #pragma unroll
            for (int ni = 0; ni < 4; ++ni)
                bf[ni] = *(const bf16x8*)(&Bs[(j * 128 + n_off + ni * 16 + ln16) * AS + quad * 8]);
            #pragma unroll
            for (int mi = 0; mi < 2; ++mi)
                #pragma unroll
                for (int ni = 0; ni < 4; ++ni)
                    acc[mi][ni] = __builtin_amdgcn_mfma_f32_16x16x32_bf16(af[mi], bf[ni], acc[mi][ni], 0, 0, 0);
        }
        __syncthreads();
    }

    // epilogue: D layout col=lane&15 (n), row=quad*4+reg (m)
    #pragma unroll
    for (int ni = 0; ni < 4; ++ni) {
        int n = n0 + n_off + ni * 16 + ln16;
        float bv = bias[n];
        #pragma unroll
        for (int mi = 0; mi < 2; ++mi) {
            #pragma unroll
            for (int r = 0; r < 4; ++r) {
                int m = m_off + mi * 16 + quad * 4 + r;
                int t = t0 + m;
                float v = fmaxf(acc[mi][ni][r] + bv, 0.f);
                size_t oi = ((size_t)b * T + t) * N + n;
                if constexpr (OUT_BF16) ((ushort*)outv)[oi] = f2bf(v);
                else                    ((float*)outv)[oi]  = v;
            }
        }
    }
}

// ---------------- head conv3: 256 -> 1, k=1, tanh ----------------
__global__ __launch_bounds__(256) void k_conv3(
    const float* __restrict__ out2, const float* __restrict__ W3,
    const float* __restrict__ b3, float* __restrict__ out)
{
    int wid = threadIdx.x >> 6, lane = threadIdx.x & 63;
    int pos = blockIdx.x * 4 + wid;
    float4 v = *(const float4*)(out2 + (size_t)pos * 256 + lane * 4);
    float4 w = *(const float4*)(W3 + lane * 4);
    float sum = v.x * w.x + v.y * w.y + v.z * w.z + v.w * w.w;
    #pragma unroll
    for (int off = 32; off > 0; off >>= 1) sum += __shfl_down(sum, off);
    if (lane == 0) out[pos] = tanhf_(sum + b3[0]);
}

extern "C" void kernel_launch(void* const* d_in, const int* in_sizes, int n_in,
                              void* d_out, int out_size, void* d_ws, size_t ws_size,
                              hipStream_t stream)
{
    const float* x     = (const float*)d_in[0];
    const float* cond  = (const float*)d_in[1];
    const float* Wc    = (const float*)d_in[2];
    const float* bc    = (const float*)d_in[3];
    const float* Wt    = (const float*)d_in[4];
    const float* bt    = (const float*)d_in[5];
    const float* Ws    = (const float*)d_in[6];
    const float* bs    = (const float*)d_in[7];
    const float* Dt    = (const float*)d_in[8];
    const float* Bt    = (const float*)d_in[9];
    const float* Ds    = (const float*)d_in[10];
    const float* Bs    = (const float*)d_in[11];
    const float* Wskip = (const float*)d_in[12];
    const float* bskip = (const float*)d_in[13];
    const float* Wres  = (const float*)d_in[14];
    const float* bres  = (const float*)d_in[15];
    const float* W1    = (const float*)d_in[16];
    const float* b1    = (const float*)d_in[17];
    const float* W2    = (const float*)d_in[18];
    const float* b2    = (const float*)d_in[19];
    const float* W3    = (const float*)d_in[20];
    const float* b3    = (const float*)d_in[21];
    float* out = (float*)d_out;

    float* ws   = (float*)d_ws;
    float* h0   = ws;                          // 2,097,152 f32
    float* h1   = ws + 2097152;                // 2,097,152 f32
    float* skip = ws + 4194304;                // 2,097,152 f32
    float* out2 = ws + 6291456;                // 4,194,304 f32 [B,T,256]
    ushort* skipb = (ushort*)(ws + 10485760);  // 2,097,152 bf16
    ushort* W1b   = skipb + 2097152;           // 786,432  bf16  [2048][384]
    ushort* W2b   = W1b + 786432;              // 1,572,864 bf16 [256][6144]
    ushort* out1b = W2b + 1572864;             // 33,554,432 bf16 [B][T][2048]

    k_init<<<8192, 256, 0, stream>>>(x, Wc, bc, h0, skip);

    static const int DIL[NLAYER] = {1, 2, 4, 8, 16, 32, 64, 128, 256, 512};
    float* hin = h0;
    float* hout = h1;
    for (int l = 0; l < NLAYER; ++l) {
        k_layer<<<T / 4, 128, 0, stream>>>(hin, hout, skip, cond,
                                           Wt, bt, Ws, bs, Dt, Bt, Ds, Bs,
                                           Wskip, bskip, Wres, bres,
                                           l, DIL[l]);
        float* tmp = hin; hin = hout; hout = tmp;
    }

    // prep: skip -> bf16, W1/W2 -> transposed bf16
    k_f32_to_bf16<<<(BATCH * T * C + 255) / 256, 256, 0, stream>>>(skip, skipb, BATCH * T * C);
    k_prep_w<128><<<2048, 384, 0, stream>>>(W1, W1b, 2048);
    k_prep_w<2048><<<256, 1024, 0, stream>>>(W2, W2b, 256);

    // head GEMMs via MFMA
    k_conv_mfma<128, true><<<dim3(T / 64, 16, BATCH), 256, 0, stream>>>(skipb, W1b, b1, out1b);
    k_conv_mfma<2048, false><<<dim3(T / 64, 2, BATCH), 256, 0, stream>>>(out1b, W2b, b2, out2);

    k_conv3<<<(BATCH * T) / 4, 256, 0, stream>>>(out2, W3, b3, out);
}

// Round 3
// 1040.051 us; speedup vs baseline: 3.7912x; 1.9351x over previous
//
#include <hip/hip_runtime.h>
#include <hip/hip_bf16.h>
#include <math.h>

#define T 2048
#define C 128
#define BATCH 8
#define NLAYER 10

typedef short bf16x8 __attribute__((ext_vector_type(8)));
typedef float f32x4 __attribute__((ext_vector_type(4)));

__device__ __forceinline__ float sigmoidf_(float x) {
    return 1.f / (1.f + __expf(-x));
}
__device__ __forceinline__ float tanhf_(float x) {
    float a = fabsf(x);
    float e = __expf(-2.f * a);
    float t = (1.f - e) / (1.f + e);
    return copysignf(t, x);
}
__device__ __forceinline__ ushort f2bf(float v) {
    __hip_bfloat16 h = __float2bfloat16(v);
    return *reinterpret_cast<ushort*>(&h);
}
__device__ __forceinline__ float bf2f(ushort u) {
    unsigned int x = ((unsigned int)u) << 16;
    return __uint_as_float(x);
}

// ---------------- init: h = x*Wc + bc (f32 + bf16) ; skip = 0 ----------------
__global__ void k_init(const float* __restrict__ x, const float* __restrict__ Wc,
                       const float* __restrict__ bc, float* __restrict__ h32,
                       ushort* __restrict__ hb, float* __restrict__ skip) {
    int i = blockIdx.x * 256 + threadIdx.x;   // over B*T*C
    int c = i & 127;
    int pos = i >> 7;
    float v = x[pos] * Wc[c] + bc[c];
    h32[i] = v;
    hb[i] = f2bf(v);
    skip[i] = 0.f;
}

// ---------------- weight preps (one-time, bf16 transposed) ----------------
// WGb[l][n 0..255][k = j*128+ci]:  n<128 -> Wt col n ; n>=128 -> Ws col n-128
__global__ void k_prep_wg(const float* __restrict__ Wt, const float* __restrict__ Ws,
                          ushort* __restrict__ WGb) {
    int n = blockIdx.x;           // 0..255
    int l = blockIdx.y;
    int t = threadIdx.x;          // 0..383 : j = t>>7, ci = t&127
    int j = t >> 7, ci = t & 127;
    const float* src = (n < 128) ? Wt : Ws;
    int col = n & 127;
    WGb[((size_t)(l * 256 + n)) * 384 + t] = f2bf(src[(((size_t)l * 3 + j) * 128 + ci) * 128 + col]);
}
// WRb[l][n 0..255][ci]: n<128 -> Wskip col n ; n>=128 -> Wres col n-128
__global__ void k_prep_wr(const float* __restrict__ Wskip, const float* __restrict__ Wres,
                          ushort* __restrict__ WRb) {
    int n = blockIdx.x;
    int l = blockIdx.y;
    int ci = threadIdx.x;         // 0..127
    const float* src = (n < 128) ? Wskip : Wres;
    int col = n & 127;
    WRb[((size_t)(l * 256 + n)) * 128 + ci] = f2bf(src[((size_t)l * 128 + ci) * 128 + col]);
}
// W [3][KIN][N] f32 -> Wb [N][3*KIN] bf16; grid.x = N (head weights)
template<int KIN>
__global__ void k_prep_w(const float* __restrict__ W, ushort* __restrict__ Wb, int N) {
    int n = blockIdx.x;
    for (int k = threadIdx.x; k < 3 * KIN; k += blockDim.x)
        Wb[(size_t)n * (3 * KIN) + k] = f2bf(W[(size_t)k * N + n]);
}
__global__ void k_f32_to_bf16(const float* __restrict__ in, ushort* __restrict__ out, int n) {
    int i = blockIdx.x * 256 + threadIdx.x;
    if (i < n) out[i] = f2bf(in[i]);
}

// ---------------- conditioning precompute (5-layer chunk) ----------------
// z0[ll][b][t][n] bf16 = conv-bias + B + sum_c cond[b,c]*D[l,c,t,k]
// n<128: tanh branch (Dt/Bt/bt), n>=128: sigmoid branch (Ds/Bs/bs)
__global__ __launch_bounds__(256) void k_cond(
    const float* __restrict__ cond,
    const float* __restrict__ Dt, const float* __restrict__ Bt,
    const float* __restrict__ Ds, const float* __restrict__ Bs,
    const float* __restrict__ bt, const float* __restrict__ bs,
    ushort* __restrict__ z0, int l0)
{
    int l = l0 + blockIdx.y;
    int ll = blockIdx.y;
    int t0 = blockIdx.x * 8;
    int k = threadIdx.x & 127;
    int th = threadIdx.x >> 7;       // 0/1 -> which 4 t
    __shared__ float sc[128];
    if (threadIdx.x < 128) sc[threadIdx.x] = cond[threadIdx.x];
    __syncthreads();
    float btv = bt[l * 128 + k], bsv = bs[l * 128 + k];
    for (int pp = 0; pp < 4; ++pp) {
        int t = t0 + th * 4 + pp;
        float zt[8], zs[8];
        float Btv = Bt[((size_t)l * T + t) * 128 + k];
        float Bsv = Bs[((size_t)l * T + t) * 128 + k];
        #pragma unroll
        for (int b = 0; b < 8; ++b) { zt[b] = btv + Btv; zs[b] = bsv + Bsv; }
        #pragma unroll
        for (int c = 0; c < 16; ++c) {
            float dt = Dt[(((size_t)l * 16 + c) * T + t) * 128 + k];
            float ds = Ds[(((size_t)l * 16 + c) * T + t) * 128 + k];
            #pragma unroll
            for (int b = 0; b < 8; ++b) {
                zt[b] = fmaf(sc[b * 16 + c], dt, zt[b]);
                zs[b] = fmaf(sc[b * 16 + c], ds, zs[b]);
            }
        }
        #pragma unroll
        for (int b = 0; b < 8; ++b) {
            size_t zb = (((size_t)ll * 8 + b) * T + t) * 256;
            z0[zb + k]       = f2bf(zt[b]);
            z0[zb + 128 + k] = f2bf(zs[b]);
        }
    }
}

// ---------------- fused MFMA WaveNet layer ----------------
// grid 512 (t-tile of 4, all 8 batches -> M=32 rows, r = p*8+b), block 256 (4 waves)
// wave w owns n = w*64 .. w*64+63 across all 32 rows.
// GEMM1: A = h taps (3 LDS segs), B = WG[l] (global, L2-hot), N=256=[t||s], K=384
// epilogue: +z0, exchange via LDS, gate, GEMM2 (g x WR[l], K=128) -> skip/res
__global__ __launch_bounds__(256) void k_gate(
    const float* __restrict__ h32_in, float* __restrict__ h32_out,
    const ushort* __restrict__ hb_in, ushort* __restrict__ hb_out,
    float* __restrict__ skip32,
    const ushort* __restrict__ WG,   // [256][384] (layer slice)
    const ushort* __restrict__ WR,   // [256][128]
    const ushort* __restrict__ z0l,  // [8][T][256]
    const float* __restrict__ bskip, const float* __restrict__ bres, // [128] slices
    int d)
{
    __shared__ ushort lds[3 * 32 * 136];   // 13056 ushorts = 26112 B
    // region reuse: zbuf = lds[0 .. 32*264)  (after GEMM1); gbuf = lds + 8704 (seg-2 area)
    const int tid  = threadIdx.x;
    const int lane = tid & 63, ln16 = lane & 15, quad = lane >> 4;
    const int wave = tid >> 6;
    const int n_off = wave * 64;
    const int t0 = blockIdx.x * 4;

    // stage A: 3 segs x 32 rows x 256 B
    #pragma unroll
    for (int it = 0; it < 6; ++it) {
        int task = tid + it * 256;        // [0, 1536)
        int part = task & 15;
        int r = (task >> 4) & 31;
        int j = task >> 9;
        int t = t0 + (r >> 3) + (j - 1) * d;
        int b = r & 7;
        uint4 v = make_uint4(0u, 0u, 0u, 0u);
        if (t >= 0 && t < T) v = *(const uint4*)(hb_in + ((size_t)b * T + t) * 128 + part * 8);
        *(uint4*)(&lds[(j * 32 + r) * 136 + part * 8]) = v;
    }
    __syncthreads();

    f32x4 acc[2][4];
    #pragma unroll
    for (int mt = 0; mt < 2; ++mt)
        #pragma unroll
        for (int nt = 0; nt < 4; ++nt)
            acc[mt][nt] = (f32x4){0.f, 0.f, 0.f, 0.f};

    #pragma unroll
    for (int j = 0; j < 3; ++j) {
        #pragma unroll
        for (int kc = 0; kc < 4; ++kc) {
            bf16x8 af[2], bfr[4];
            #pragma unroll
            for (int mt = 0; mt < 2; ++mt)
                af[mt] = *(const bf16x8*)(&lds[(j * 32 + mt * 16 + ln16) * 136 + kc * 32 + quad * 8]);
            #pragma unroll
            for (int nt = 0; nt < 4; ++nt)
                bfr[nt] = *(const bf16x8*)(WG + (size_t)(n_off + nt * 16 + ln16) * 384 + j * 128 + kc * 32 + quad * 8);
            #pragma unroll
            for (int mt = 0; mt < 2; ++mt)
                #pragma unroll
                for (int nt = 0; nt < 4; ++nt)
                    acc[mt][nt] = __builtin_amdgcn_mfma_f32_16x16x32_bf16(af[mt], bfr[nt], acc[mt][nt], 0, 0, 0);
        }
    }
    __syncthreads();   // A segs dead

    // epilogue-1: add z0, stash pre-activations in zbuf (bf16)
    #pragma unroll
    for (int mt = 0; mt < 2; ++mt) {
        #pragma unroll
        for (int nt = 0; nt < 4; ++nt) {
            int n = n_off + nt * 16 + ln16;
            #pragma unroll
            for (int r4 = 0; r4 < 4; ++r4) {
                int row = mt * 16 + quad * 4 + r4;
                int b = row & 7, p = row >> 3;
                float z = acc[mt][nt][r4] + bf2f(z0l[((size_t)b * T + t0 + p) * 256 + n]);
                lds[row * 264 + n] = f2bf(z);
            }
        }
    }
    __syncthreads();

    // gate: g = tanh(zt) * sigmoid(zs) -> gbuf [32][136]
    {
        int r = tid >> 3;              // 0..31
        int k0 = (tid & 7) * 16;       // 0..127 step 16
        #pragma unroll
        for (int kk = 0; kk < 16; ++kk) {
            int k = k0 + kk;
            float zt = bf2f(lds[r * 264 + k]);
            float zs = bf2f(lds[r * 264 + 128 + k]);
            lds[8704 + r * 136 + k] = f2bf(tanhf_(zt) * sigmoidf_(zs));
        }
    }
    __syncthreads();

    // GEMM2: skip/res 1x1 convs, K=128
    f32x4 acc2[2][4];
    #pragma unroll
    for (int mt = 0; mt < 2; ++mt)
        #pragma unroll
        for (int nt = 0; nt < 4; ++nt)
            acc2[mt][nt] = (f32x4){0.f, 0.f, 0.f, 0.f};

    #pragma unroll
    for (int kc = 0; kc < 4; ++kc) {
        bf16x8 af[2], bfr[4];
        #pragma unroll
        for (int mt = 0; mt < 2; ++mt)
            af[mt] = *(const bf16x8*)(&lds[8704 + (mt * 16 + ln16) * 136 + kc * 32 + quad * 8]);
        #pragma unroll
        for (int nt = 0; nt < 4; ++nt)
            bfr[nt] = *(const bf16x8*)(WR + (size_t)(n_off + nt * 16 + ln16) * 128 + kc * 32 + quad * 8);
        #pragma unroll
        for (int mt = 0; mt < 2; ++mt)
            #pragma unroll
            for (int nt = 0; nt < 4; ++nt)
                acc2[mt][nt] = __builtin_amdgcn_mfma_f32_16x16x32_bf16(af[mt], bfr[nt], acc2[mt][nt], 0, 0, 0);
    }

    // epilogue-2: waves 0/1 (n<128) -> skip accum; waves 2/3 -> residual h
    #pragma unroll
    for (int mt = 0; mt < 2; ++mt) {
        #pragma unroll
        for (int nt = 0; nt < 4; ++nt) {
            int n = n_off + nt * 16 + ln16;
            int k = n & 127;
            #pragma unroll
            for (int r4 = 0; r4 < 4; ++r4) {
                int row = mt * 16 + quad * 4 + r4;
                int b = row & 7, p = row >> 3;
                size_t idx = ((size_t)b * T + t0 + p) * 128 + k;
                float v = acc2[mt][nt][r4];
                if (n < 128) {
                    skip32[idx] += v + bskip[k];
                } else {
                    float hv = v + bres[k] + h32_in[idx];
                    h32_out[idx] = hv;
                    hb_out[idx] = f2bf(hv);
                }
            }
        }
    }
}

// ---------------- MFMA conv head (unchanged structure from round 2) ----------------
template<int KIN, bool OUT_BF16>
__global__ __launch_bounds__(256) void k_conv_mfma(
    const ushort* __restrict__ A, const ushort* __restrict__ Wb,
    const float* __restrict__ bias, void* __restrict__ outv,
    int b_in_off, int b_out_off)
{
    constexpr int AS = 40;
    __shared__ ushort As[66 * AS];
    __shared__ ushort Bs[3 * 128 * AS];

    const int tid  = threadIdx.x;
    const int lane = tid & 63;
    const int ln16 = lane & 15;
    const int quad = lane >> 4;
    const int wave = tid >> 6;
    const int m_off = (wave & 1) * 32;
    const int n_off = (wave >> 1) * 64;

    const int t0 = blockIdx.x * 64;
    const int n0 = blockIdx.y * 128;
    const int bz = blockIdx.z;
    const int N  = gridDim.y * 128;

    const ushort* Ab = A + (size_t)(b_in_off + bz) * T * KIN;

    f32x4 acc[2][4];
    #pragma unroll
    for (int mi = 0; mi < 2; ++mi)
        #pragma unroll
        for (int ni = 0; ni < 4; ++ni)
            acc[mi][ni] = (f32x4){0.f, 0.f, 0.f, 0.f};

    for (int cc = 0; cc < KIN / 32; ++cc) {
        for (int idx = tid; idx < 66 * 4; idx += 256) {
            int r = idx >> 2, part = idx & 3;
            int t = t0 - 1 + r;
            uint4 v = make_uint4(0u, 0u, 0u, 0u);
            if (t >= 0 && t < T)
                v = *(const uint4*)(Ab + (size_t)t * KIN + cc * 32 + part * 8);
            *(uint4*)(&As[r * AS + part * 8]) = v;
        }
        #pragma unroll
        for (int it = 0; it < 6; ++it) {
            int idx = tid + it * 256;
            int jr = idx >> 2, part = idx & 3;
            int j = jr >> 7, n = jr & 127;
            uint4 v = *(const uint4*)(Wb + (size_t)(n0 + n) * (3 * KIN) + j * KIN + cc * 32 + part * 8);
            *(uint4*)(&Bs[jr * AS + part * 8]) = v;
        }
        __syncthreads();

        #pragma unroll
        for (int j = 0; j < 3; ++j) {
            bf16x8 af[2], bf[4];
            #pragma unroll
            for (int mi = 0; mi < 2; ++mi)
                af[mi] = *(const bf16x8*)(&As[(m_off + mi * 16 + ln16 + j) * AS + quad * 8]);
            #pragma unroll
            for (int ni = 0; ni < 4; ++ni)
                bf[ni] = *(const bf16x8*)(&Bs[(j * 128 + n_off + ni * 16 + ln16) * AS + quad * 8]);
            #pragma unroll
            for (int mi = 0; mi < 2; ++mi)
                #pragma unroll
                for (int ni = 0; ni < 4; ++ni)
                    acc[mi][ni] = __builtin_amdgcn_mfma_f32_16x16x32_bf16(af[mi], bf[ni], acc[mi][ni], 0, 0, 0);
        }
        __syncthreads();
    }

    #pragma unroll
    for (int ni = 0; ni < 4; ++ni) {
        int n = n0 + n_off + ni * 16 + ln16;
        float bv = bias[n];
        #pragma unroll
        for (int mi = 0; mi < 2; ++mi) {
            #pragma unroll
            for (int r = 0; r < 4; ++r) {
                int m = m_off + mi * 16 + quad * 4 + r;
                int t = t0 + m;
                float v = fmaxf(acc[mi][ni][r] + bv, 0.f);
                size_t oi = ((size_t)(b_out_off + bz) * T + t) * N + n;
                if constexpr (OUT_BF16) ((ushort*)outv)[oi] = f2bf(v);
                else                    ((float*)outv)[oi]  = v;
            }
        }
    }
}

// ---------------- head conv3: 256 -> 1, k=1, tanh ----------------
__global__ __launch_bounds__(256) void k_conv3(
    const float* __restrict__ out2, const float* __restrict__ W3,
    const float* __restrict__ b3, float* __restrict__ out)
{
    int wid = threadIdx.x >> 6, lane = threadIdx.x & 63;
    int pos = blockIdx.x * 4 + wid;
    float4 v = *(const float4*)(out2 + (size_t)pos * 256 + lane * 4);
    float4 w = *(const float4*)(W3 + lane * 4);
    float sum = v.x * w.x + v.y * w.y + v.z * w.z + v.w * w.w;
    #pragma unroll
    for (int off = 32; off > 0; off >>= 1) sum += __shfl_down(sum, off);
    if (lane == 0) out[pos] = tanhf_(sum + b3[0]);
}

extern "C" void kernel_launch(void* const* d_in, const int* in_sizes, int n_in,
                              void* d_out, int out_size, void* d_ws, size_t ws_size,
                              hipStream_t stream)
{
    const float* x     = (const float*)d_in[0];
    const float* cond  = (const float*)d_in[1];
    const float* Wc    = (const float*)d_in[2];
    const float* bc    = (const float*)d_in[3];
    const float* Wt    = (const float*)d_in[4];
    const float* bt    = (const float*)d_in[5];
    const float* Ws    = (const float*)d_in[6];
    const float* bs    = (const float*)d_in[7];
    const float* Dt    = (const float*)d_in[8];
    const float* Bt    = (const float*)d_in[9];
    const float* Ds    = (const float*)d_in[10];
    const float* Bs    = (const float*)d_in[11];
    const float* Wskip = (const float*)d_in[12];
    const float* bskip = (const float*)d_in[13];
    const float* Wres  = (const float*)d_in[14];
    const float* bres  = (const float*)d_in[15];
    const float* W1    = (const float*)d_in[16];
    const float* b1    = (const float*)d_in[17];
    const float* W2    = (const float*)d_in[18];
    const float* b2    = (const float*)d_in[19];
    const float* W3    = (const float*)d_in[20];
    const float* b3    = (const float*)d_in[21];
    float* out = (float*)d_out;

    float* ws = (float*)d_ws;
    float*  skip32 = ws;                       // 2M f32
    float*  h32a   = ws + 2097152;             // 2M f32
    float*  h32b   = ws + 4194304;             // 2M f32
    float*  out2   = ws + 6291456;             // 4M f32
    ushort* u      = (ushort*)(ws + 10485760);
    ushort* hba    = u;                        // 2M us
    ushort* hbb    = u + 2097152;              // 2M us
    ushort* WGb    = u + 4194304;              // 983,040 us
    ushort* WRb    = u + 5177344;              // 327,680 us
    ushort* W1b    = u + 5505024;              // 786,432 us
    ushort* W2b    = u + 6291456;              // 1,572,864 us
    ushort* skipb  = u + 7864320;              // 2M us
    ushort* z0     = u + 9961472;              // 5*8*T*256 = 20,971,520 us
    ushort* out1b  = z0;                       // reuses z0 region for the head

    // choose head batch chunk vs ws_size (z0 end needs ~103.8 MB; known ws >= 117 MB)
    int nb = 8;
    while (nb > 1) {
        size_t need = 41943040ull + 2ull * (9961472ull + (size_t)nb * 4194304ull);
        if (need <= ws_size) break;
        nb >>= 1;
    }

    k_init<<<8192, 256, 0, stream>>>(x, Wc, bc, h32a, hba, skip32);
    k_prep_wg<<<dim3(256, NLAYER), 384, 0, stream>>>(Wt, Ws, WGb);
    k_prep_wr<<<dim3(256, NLAYER), 128, 0, stream>>>(Wskip, Wres, WRb);
    k_prep_w<128><<<2048, 384, 0, stream>>>(W1, W1b, 2048);
    k_prep_w<2048><<<256, 1024, 0, stream>>>(W2, W2b, 256);

    static const int DIL[NLAYER] = {1, 2, 4, 8, 16, 32, 64, 128, 256, 512};
    float*  h32in = h32a;  float*  h32out = h32b;
    ushort* hbin  = hba;   ushort* hbout  = hbb;

    for (int chunk = 0; chunk < 2; ++chunk) {
        int l0 = chunk * 5;
        k_cond<<<dim3(256, 5), 256, 0, stream>>>(cond, Dt, Bt, Ds, Bs, bt, bs, z0, l0);
        for (int l = l0; l < l0 + 5; ++l) {
            k_gate<<<512, 256, 0, stream>>>(
                h32in, h32out, hbin, hbout, skip32,
                WGb + (size_t)l * 256 * 384,
                WRb + (size_t)l * 256 * 128,
                z0 + (size_t)(l - l0) * 8 * T * 256,
                bskip + l * 128, bres + l * 128,
                DIL[l]);
            float* tf = h32in; h32in = h32out; h32out = tf;
            ushort* tu = hbin; hbin = hbout; hbout = tu;
        }
    }

    k_f32_to_bf16<<<(BATCH * T * C + 255) / 256, 256, 0, stream>>>(skip32, skipb, BATCH * T * C);

    for (int b0 = 0; b0 < BATCH; b0 += nb) {
        int nbc = (b0 + nb <= BATCH) ? nb : (BATCH - b0);
        k_conv_mfma<128, true><<<dim3(T / 64, 16, nbc), 256, 0, stream>>>(skipb, W1b, b1, out1b, b0, 0);
        k_conv_mfma<2048, false><<<dim3(T / 64, 2, nbc), 256, 0, stream>>>(out1b, W2b, b2, out2, 0, b0);
    }

    k_conv3<<<(BATCH * T) / 4, 256, 0, stream>>>(out2, W3, b3, out);
}